// Round 1
// baseline (765.297 us; speedup 1.0000x reference)
//
#include <hip/hip_runtime.h>

#define NN 50000
#define NE 800000
#define NB 64
#define DIM 64
#define TM 128   // nodes per block in mlp kernel

// ws layout (floats): sums[NN*DIM] | counts[NN] | U1[NB*DIM]
// zeroed region = sums + counts = NN*DIM + NN floats = 3,250,000 (divisible by 4)

__global__ __launch_bounds__(256) void zero_k(float4* __restrict__ p, int n4) {
    int i = blockIdx.x * 256 + threadIdx.x;
    if (i < n4) p[i] = make_float4(0.f, 0.f, 0.f, 0.f);
}

// one float4 chunk of one edge per thread; 16 threads per edge
__global__ __launch_bounds__(256) void scatter_k(
    const int* __restrict__ eidx,        // [2*NE], row 0 = src
    const float4* __restrict__ ea,       // [NE*16] float4 view of [NE,64]
    float* __restrict__ sums, float* __restrict__ counts)
{
    int t = blockIdx.x * 256 + threadIdx.x;   // grid exactly NE*16 threads
    int e = t >> 4, c = t & 15;
    int s = eidx[e];
    float4 v = ea[t];
    float* dst = sums + (size_t)s * DIM + c * 4;
    atomicAdd(dst + 0, v.x);
    atomicAdd(dst + 1, v.y);
    atomicAdd(dst + 2, v.z);
    atomicAdd(dst + 3, v.w);
    if (c == 0) atomicAdd(counts + s, 1.0f);
}

// U1[b][j] = b1[j] + sum_k u[b][k] * W1[128+k][j]
__global__ __launch_bounds__(64) void premix_k(
    const float* __restrict__ u, const float* __restrict__ W1,
    const float* __restrict__ b1, float* __restrict__ U1)
{
    int b = blockIdx.x, j = threadIdx.x;
    float acc = b1[j];
    const float* up = u + b * DIM;
    #pragma unroll 8
    for (int k = 0; k < DIM; ++k)
        acc = fmaf(up[k], W1[(2 * DIM + k) * DIM + j], acc);
    U1[b * DIM + j] = acc;
}

#define LDA 132  // padded row stride for A (16B-aligned rows, breaks pow2 banks)

__device__ __forceinline__ void gemm_step(float acc[8][4],
                                          const float* __restrict__ A,
                                          const float* __restrict__ Wb,
                                          int NG, int DG)
{
    #pragma unroll 4
    for (int k = 0; k < 64; ++k) {
        const float4 w  = *(const float4*)&Wb[k * 64 + DG];
        const float4 a0 = *(const float4*)&A[k * LDA + NG];
        const float4 a1 = *(const float4*)&A[k * LDA + NG + 4];
        const float av[8] = {a0.x, a0.y, a0.z, a0.w, a1.x, a1.y, a1.z, a1.w};
        const float wv[4] = {w.x, w.y, w.z, w.w};
        #pragma unroll
        for (int i = 0; i < 8; ++i)
            #pragma unroll
            for (int j = 0; j < 4; ++j)
                acc[i][j] = fmaf(av[i], wv[j], acc[i][j]);
    }
}

__global__ __launch_bounds__(256) void mlp_k(
    const float* __restrict__ x, const int* __restrict__ batch,
    const float* __restrict__ W1, const float* __restrict__ W2,
    const float* __restrict__ b2, const float* __restrict__ sums,
    const float* __restrict__ counts, const float* __restrict__ U1,
    float* __restrict__ out)
{
    __shared__ float A[64 * LDA];   // activations transposed: A[k][n_local]
    __shared__ float Wb[64 * 64];   // current 64x64 weight block

    const int t = threadIdx.x;
    const int c = t & 15;           // staging: column group (k-chunk of 4)
    const int rbase = t >> 4;       // staging: row within tile
    const int DG = (t & 15) * 4;    // this thread's 4 output dims
    const int NG = (t >> 4) * 8;    // this thread's 8 local nodes
    const int n0 = blockIdx.x * TM;

    float acc[8][4];

    // init acc = U1[batch[n]][DG..DG+3]
    #pragma unroll
    for (int i = 0; i < 8; ++i) {
        int n = n0 + NG + i;
        int b = (n < NN) ? batch[n] : 0;
        const float4 uv = *(const float4*)&U1[b * DIM + DG];
        acc[i][0] = uv.x; acc[i][1] = uv.y; acc[i][2] = uv.z; acc[i][3] = uv.w;
    }

    // ---------- pass 1: x @ W1[0:64] ----------
    #pragma unroll
    for (int it = 0; it < 8; ++it) {
        int r = rbase + it * 16;
        int n = n0 + r;
        float4 v = make_float4(0.f, 0.f, 0.f, 0.f);
        if (n < NN) v = *(const float4*)&x[(size_t)n * DIM + c * 4];
        A[(c * 4 + 0) * LDA + r] = v.x;
        A[(c * 4 + 1) * LDA + r] = v.y;
        A[(c * 4 + 2) * LDA + r] = v.z;
        A[(c * 4 + 3) * LDA + r] = v.w;
    }
    #pragma unroll
    for (int it = 0; it < 4; ++it) {
        int r = rbase + it * 16;
        *(float4*)&Wb[r * 64 + c * 4] = *(const float4*)&W1[(size_t)r * DIM + c * 4];
    }
    __syncthreads();
    gemm_step(acc, A, Wb, NG, DG);
    __syncthreads();

    // ---------- pass 2: v_e @ W1[64:128] ----------
    #pragma unroll
    for (int it = 0; it < 8; ++it) {
        int r = rbase + it * 16;
        int n = n0 + r;
        float4 v = make_float4(0.f, 0.f, 0.f, 0.f);
        if (n < NN) {
            float rs = 1.0f / fmaxf(counts[n], 1.0f);
            v = *(const float4*)&sums[(size_t)n * DIM + c * 4];
            v.x *= rs; v.y *= rs; v.z *= rs; v.w *= rs;
        }
        A[(c * 4 + 0) * LDA + r] = v.x;
        A[(c * 4 + 1) * LDA + r] = v.y;
        A[(c * 4 + 2) * LDA + r] = v.z;
        A[(c * 4 + 3) * LDA + r] = v.w;
    }
    #pragma unroll
    for (int it = 0; it < 4; ++it) {
        int r = rbase + it * 16;
        *(float4*)&Wb[r * 64 + c * 4] = *(const float4*)&W1[(size_t)(64 + r) * DIM + c * 4];
    }
    __syncthreads();
    gemm_step(acc, A, Wb, NG, DG);

    // relu
    #pragma unroll
    for (int i = 0; i < 8; ++i)
        #pragma unroll
        for (int j = 0; j < 4; ++j)
            acc[i][j] = fmaxf(acc[i][j], 0.f);

    __syncthreads();   // everyone done reading A/Wb

    // ---------- layer 2: h @ W2 ----------
    // write h^T into A: rows DG+j, cols NG..NG+7
    #pragma unroll
    for (int j = 0; j < 4; ++j) {
        float4 h0 = make_float4(acc[0][j], acc[1][j], acc[2][j], acc[3][j]);
        float4 h1 = make_float4(acc[4][j], acc[5][j], acc[6][j], acc[7][j]);
        *(float4*)&A[(DG + j) * LDA + NG]     = h0;
        *(float4*)&A[(DG + j) * LDA + NG + 4] = h1;
    }
    #pragma unroll
    for (int it = 0; it < 4; ++it) {
        int r = rbase + it * 16;
        *(float4*)&Wb[r * 64 + c * 4] = *(const float4*)&W2[(size_t)r * DIM + c * 4];
    }
    __syncthreads();

    // acc = b2
    {
        const float4 bv = *(const float4*)&b2[DG];
        #pragma unroll
        for (int i = 0; i < 8; ++i) {
            acc[i][0] = bv.x; acc[i][1] = bv.y; acc[i][2] = bv.z; acc[i][3] = bv.w;
        }
    }
    gemm_step(acc, A, Wb, NG, DG);

    // store
    #pragma unroll
    for (int i = 0; i < 8; ++i) {
        int n = n0 + NG + i;
        if (n < NN) {
            float4 o = make_float4(acc[i][0], acc[i][1], acc[i][2], acc[i][3]);
            *(float4*)&out[(size_t)n * DIM + DG] = o;
        }
    }
}

extern "C" void kernel_launch(void* const* d_in, const int* in_sizes, int n_in,
                              void* d_out, int out_size, void* d_ws, size_t ws_size,
                              hipStream_t stream)
{
    const float* x     = (const float*)d_in[0];
    const int*   eidx  = (const int*)d_in[1];    // [2,E] int32, row 0 = src
    const float* ea    = (const float*)d_in[2];
    const float* u     = (const float*)d_in[3];
    const int*   batch = (const int*)d_in[4];
    const float* W1    = (const float*)d_in[5];
    const float* b1    = (const float*)d_in[6];
    const float* W2    = (const float*)d_in[7];
    const float* b2    = (const float*)d_in[8];
    float* out = (float*)d_out;

    float* ws     = (float*)d_ws;
    float* sums   = ws;                       // NN*DIM
    float* counts = ws + (size_t)NN * DIM;    // NN
    float* U1     = counts + NN;              // NB*DIM

    // zero sums + counts (3,250,000 floats = 812,500 float4)
    {
        int n4 = (NN * DIM + NN) / 4;
        zero_k<<<(n4 + 255) / 256, 256, 0, stream>>>((float4*)ws, n4);
    }
    scatter_k<<<(NE * 16) / 256, 256, 0, stream>>>(eidx, (const float4*)ea, sums, counts);
    premix_k<<<NB, DIM, 0, stream>>>(u, W1, b1, U1);
    mlp_k<<<(NN + TM - 1) / TM, 256, 0, stream>>>(x, batch, W1, W2, b2, sums, counts, U1, out);
}

// Round 2
// 278.615 us; speedup vs baseline: 2.7468x; 2.7468x over previous
//
#include <hip/hip_runtime.h>

#define NN 50000
#define NE 800000
#define NB 64
#define DIM 64
#define TM 128     // nodes per block in mlp kernel
#define SCAN_T 1024
#define CHUNK 49   // ceil(NN / SCAN_T)

// ws layout (ints/floats):
//   hist[NN] | offsets[NN+1] | cursor[NN] | eids[NE] | U1[NB*DIM floats]
// total ~3.8 MB. v_e is staged in d_out (each mlp block reads only its own
// rows before overwriting them, so the aliasing is block-local and ordered).

__global__ __launch_bounds__(256) void zero_k(int4* __restrict__ p, int n4) {
    int i = blockIdx.x * 256 + threadIdx.x;
    if (i < n4) p[i] = make_int4(0, 0, 0, 0);
}

__global__ __launch_bounds__(256) void hist_k(const int* __restrict__ src,
                                              int* __restrict__ hist) {
    int t = blockIdx.x * 256 + threadIdx.x;   // grid exactly NE
    atomicAdd(&hist[src[t]], 1);
}

__global__ __launch_bounds__(SCAN_T) void prefix_k(const int* __restrict__ hist,
                                                   int* __restrict__ offsets,
                                                   int* __restrict__ cursor) {
    __shared__ int part[SCAN_T];
    int t = threadIdx.x;
    int lo = t * CHUNK, hi = min(lo + CHUNK, NN);
    int s = 0;
    for (int j = lo; j < hi; ++j) s += hist[j];
    part[t] = s;
    __syncthreads();
    for (int d = 1; d < SCAN_T; d <<= 1) {
        int v = (t >= d) ? part[t - d] : 0;
        __syncthreads();
        part[t] += v;
        __syncthreads();
    }
    int run = (t == 0) ? 0 : part[t - 1];
    for (int j = lo; j < hi; ++j) {
        offsets[j] = run;
        cursor[j]  = run;
        run += hist[j];
    }
    if (t == SCAN_T - 1) offsets[NN] = run;   // == NE
}

__global__ __launch_bounds__(256) void fill_k(const int* __restrict__ src,
                                              int* __restrict__ cursor,
                                              int* __restrict__ eids) {
    int t = blockIdx.x * 256 + threadIdx.x;   // grid exactly NE
    int pos = atomicAdd(&cursor[src[t]], 1);
    eids[pos] = t;
}

// one wave per node: 4 edge slots x 16 float4 chunks; v_e -> d_out rows
__global__ __launch_bounds__(256) void reduce_k(const int* __restrict__ offsets,
                                                const int* __restrict__ eids,
                                                const float4* __restrict__ ea4,
                                                float4* ve4) {
    int n = (blockIdx.x * 256 + threadIdx.x) >> 6;   // grid exactly NN*64
    int lane = threadIdx.x & 63;
    int chunk = lane & 15, slot = lane >> 4;
    int base = offsets[n];
    int deg = offsets[n + 1] - base;
    float4 acc = make_float4(0.f, 0.f, 0.f, 0.f);
    for (int j = slot; j < deg; j += 4) {
        int e = eids[base + j];
        float4 v = ea4[(size_t)e * 16 + chunk];
        acc.x += v.x; acc.y += v.y; acc.z += v.z; acc.w += v.w;
    }
    #pragma unroll
    for (int m = 16; m <= 32; m <<= 1) {
        acc.x += __shfl_xor(acc.x, m, 64);
        acc.y += __shfl_xor(acc.y, m, 64);
        acc.z += __shfl_xor(acc.z, m, 64);
        acc.w += __shfl_xor(acc.w, m, 64);
    }
    if (slot == 0) {
        float rs = 1.0f / fmaxf((float)deg, 1.0f);
        acc.x *= rs; acc.y *= rs; acc.z *= rs; acc.w *= rs;
        ve4[(size_t)n * 16 + chunk] = acc;
    }
}

// U1[b][j] = b1[j] + sum_k u[b][k] * W1[128+k][j]
__global__ __launch_bounds__(64) void premix_k(const float* __restrict__ u,
                                               const float* __restrict__ W1,
                                               const float* __restrict__ b1,
                                               float* __restrict__ U1) {
    int b = blockIdx.x, j = threadIdx.x;
    float acc = b1[j];
    const float* up = u + b * DIM;
    #pragma unroll 8
    for (int k = 0; k < DIM; ++k)
        acc = fmaf(up[k], W1[(2 * DIM + k) * DIM + j], acc);
    U1[b * DIM + j] = acc;
}

#define LDA 132  // padded row stride for A tile

__device__ __forceinline__ void gemm_step(float acc[8][4],
                                          const float* __restrict__ A,
                                          const float* __restrict__ Wb,
                                          int NG, int DG) {
    #pragma unroll 4
    for (int k = 0; k < 64; ++k) {
        const float4 w  = *(const float4*)&Wb[k * 64 + DG];
        const float4 a0 = *(const float4*)&A[k * LDA + NG];
        const float4 a1 = *(const float4*)&A[k * LDA + NG + 4];
        const float av[8] = {a0.x, a0.y, a0.z, a0.w, a1.x, a1.y, a1.z, a1.w};
        const float wv[4] = {w.x, w.y, w.z, w.w};
        #pragma unroll
        for (int i = 0; i < 8; ++i)
            #pragma unroll
            for (int j = 0; j < 4; ++j)
                acc[i][j] = fmaf(av[i], wv[j], acc[i][j]);
    }
}

__global__ __launch_bounds__(256) void mlp_k(const float* __restrict__ x,
                                             const int* __restrict__ batch,
                                             const float* __restrict__ W1,
                                             const float* __restrict__ W2,
                                             const float* __restrict__ b2,
                                             const float* ve,   // == out (aliased)
                                             const float* __restrict__ U1,
                                             float* out) {
    __shared__ float A[64 * LDA];
    __shared__ float Wb[64 * 64];

    const int t = threadIdx.x;
    const int c = t & 15;
    const int rbase = t >> 4;
    const int DG = (t & 15) * 4;
    const int NG = (t >> 4) * 8;
    const int n0 = blockIdx.x * TM;

    float acc[8][4];

    #pragma unroll
    for (int i = 0; i < 8; ++i) {
        int n = n0 + NG + i;
        int b = (n < NN) ? batch[n] : 0;
        const float4 uv = *(const float4*)&U1[b * DIM + DG];
        acc[i][0] = uv.x; acc[i][1] = uv.y; acc[i][2] = uv.z; acc[i][3] = uv.w;
    }

    // ---------- pass 1: x @ W1[0:64] ----------
    #pragma unroll
    for (int it = 0; it < 8; ++it) {
        int r = rbase + it * 16;
        int n = n0 + r;
        float4 v = make_float4(0.f, 0.f, 0.f, 0.f);
        if (n < NN) v = *(const float4*)&x[(size_t)n * DIM + c * 4];
        A[(c * 4 + 0) * LDA + r] = v.x;
        A[(c * 4 + 1) * LDA + r] = v.y;
        A[(c * 4 + 2) * LDA + r] = v.z;
        A[(c * 4 + 3) * LDA + r] = v.w;
    }
    #pragma unroll
    for (int it = 0; it < 4; ++it) {
        int r = rbase + it * 16;
        *(float4*)&Wb[r * 64 + c * 4] = *(const float4*)&W1[(size_t)r * DIM + c * 4];
    }
    __syncthreads();
    gemm_step(acc, A, Wb, NG, DG);
    __syncthreads();

    // ---------- pass 2: v_e @ W1[64:128] ----------
    #pragma unroll
    for (int it = 0; it < 8; ++it) {
        int r = rbase + it * 16;
        int n = n0 + r;
        float4 v = make_float4(0.f, 0.f, 0.f, 0.f);
        if (n < NN) v = *(const float4*)&ve[(size_t)n * DIM + c * 4];
        A[(c * 4 + 0) * LDA + r] = v.x;
        A[(c * 4 + 1) * LDA + r] = v.y;
        A[(c * 4 + 2) * LDA + r] = v.z;
        A[(c * 4 + 3) * LDA + r] = v.w;
    }
    #pragma unroll
    for (int it = 0; it < 4; ++it) {
        int r = rbase + it * 16;
        *(float4*)&Wb[r * 64 + c * 4] = *(const float4*)&W1[(size_t)(64 + r) * DIM + c * 4];
    }
    __syncthreads();
    gemm_step(acc, A, Wb, NG, DG);

    #pragma unroll
    for (int i = 0; i < 8; ++i)
        #pragma unroll
        for (int j = 0; j < 4; ++j)
            acc[i][j] = fmaxf(acc[i][j], 0.f);

    __syncthreads();

    // ---------- layer 2: h @ W2 ----------
    #pragma unroll
    for (int j = 0; j < 4; ++j) {
        float4 h0 = make_float4(acc[0][j], acc[1][j], acc[2][j], acc[3][j]);
        float4 h1 = make_float4(acc[4][j], acc[5][j], acc[6][j], acc[7][j]);
        *(float4*)&A[(DG + j) * LDA + NG]     = h0;
        *(float4*)&A[(DG + j) * LDA + NG + 4] = h1;
    }
    #pragma unroll
    for (int it = 0; it < 4; ++it) {
        int r = rbase + it * 16;
        *(float4*)&Wb[r * 64 + c * 4] = *(const float4*)&W2[(size_t)r * DIM + c * 4];
    }
    __syncthreads();

    {
        const float4 bv = *(const float4*)&b2[DG];
        #pragma unroll
        for (int i = 0; i < 8; ++i) {
            acc[i][0] = bv.x; acc[i][1] = bv.y; acc[i][2] = bv.z; acc[i][3] = bv.w;
        }
    }
    gemm_step(acc, A, Wb, NG, DG);

    #pragma unroll
    for (int i = 0; i < 8; ++i) {
        int n = n0 + NG + i;
        if (n < NN) {
            float4 o = make_float4(acc[i][0], acc[i][1], acc[i][2], acc[i][3]);
            *(float4*)&out[(size_t)n * DIM + DG] = o;
        }
    }
}

extern "C" void kernel_launch(void* const* d_in, const int* in_sizes, int n_in,
                              void* d_out, int out_size, void* d_ws, size_t ws_size,
                              hipStream_t stream)
{
    const float* x     = (const float*)d_in[0];
    const int*   eidx  = (const int*)d_in[1];    // [2,E], row 0 = src
    const float* ea    = (const float*)d_in[2];
    const float* u     = (const float*)d_in[3];
    const int*   batch = (const int*)d_in[4];
    const float* W1    = (const float*)d_in[5];
    const float* b1    = (const float*)d_in[6];
    const float* W2    = (const float*)d_in[7];
    const float* b2    = (const float*)d_in[8];
    float* out = (float*)d_out;

    int* wsi     = (int*)d_ws;
    int* hist    = wsi;                    // NN
    int* offsets = hist + NN;              // NN+1
    int* cursor  = offsets + NN + 1;       // NN
    int* eids    = cursor + NN;            // NE
    float* U1    = (float*)(eids + NE);    // NB*DIM

    zero_k<<<(NN / 4 + 255) / 256, 256, 0, stream>>>((int4*)hist, NN / 4);
    hist_k<<<NE / 256, 256, 0, stream>>>(eidx, hist);
    prefix_k<<<1, SCAN_T, 0, stream>>>(hist, offsets, cursor);
    fill_k<<<NE / 256, 256, 0, stream>>>(eidx, cursor, eids);
    premix_k<<<NB, DIM, 0, stream>>>(u, W1, b1, U1);
    reduce_k<<<(NN * 64) / 256, 256, 0, stream>>>(offsets, eids, (const float4*)ea, (float4*)out);
    mlp_k<<<(NN + TM - 1) / TM, 256, 0, stream>>>(x, batch, W1, W2, b2, out, U1, out);
}